// Round 3
// baseline (288.058 us; speedup 1.0000x reference)
//
#include <hip/hip_runtime.h>
#include <cstdint>
#include <cstddef>
#include <math.h>

typedef _Float16 half8 __attribute__((ext_vector_type(8)));
typedef _Float16 half4 __attribute__((ext_vector_type(4)));
typedef _Float16 half2v __attribute__((ext_vector_type(2)));
typedef float f32x4 __attribute__((ext_vector_type(4)));

#define NB  2
#define NT  2048
#define NC  1024
#define NH  16
#define ND  64

__device__ __forceinline__ void gload_lds16(const _Float16* g, _Float16* l) {
  __builtin_amdgcn_global_load_lds((const __attribute__((address_space(1))) void*)g,
                                   (__attribute__((address_space(3))) void*)l, 16, 0, 0);
}

// ---------------- convert x -> fp16 ----------------
__global__ void k_cvt_x(const float* __restrict__ x, _Float16* __restrict__ xh) {
  const int n4 = (4096 * 1024) / 4;
  int i = blockIdx.x * 256 + threadIdx.x;
  for (; i < n4; i += 2048 * 256) {
    float4 v = ((const float4*)x)[i];
    half4 h = { (_Float16)v.x, (_Float16)v.y, (_Float16)v.z, (_Float16)v.w };
    ((half4*)xh)[i] = h;
  }
}

// ------------- transpose+convert W (1024x1024) -> WT[n][k] fp16 -------------
__global__ void k_tw(const float* __restrict__ W0, const float* __restrict__ W1,
                     const float* __restrict__ W2, const float* __restrict__ W3,
                     _Float16* __restrict__ WT) {
  const float* W = (blockIdx.z == 0) ? W0 : (blockIdx.z == 1) ? W1 : (blockIdx.z == 2) ? W2 : W3;
  _Float16* out = WT + ((size_t)blockIdx.z << 20);
  __shared__ float t[32][33];
  const int x0 = blockIdx.x * 32;  // n
  const int y0 = blockIdx.y * 32;  // k
  const int tx = threadIdx.x, ty = threadIdx.y;  // (32,8)
#pragma unroll
  for (int r = 0; r < 4; ++r)
    t[ty + 8 * r][tx] = W[(size_t)(y0 + ty + 8 * r) * 1024 + x0 + tx];
  __syncthreads();
#pragma unroll
  for (int r = 0; r < 4; ++r)
    out[(size_t)(x0 + ty + 8 * r) * 1024 + y0 + tx] = (_Float16)t[tx][ty + 8 * r];
}

// ---------------- shared GEMM mainloop: C(128x128) = A(128xK) * B^T(128xK) ----------------
__device__ __forceinline__ void gemm_mainloop(const _Float16* __restrict__ A,
                                              const _Float16* __restrict__ Bmat,
                                              int m0, int n0,
                                              _Float16* As, _Float16* Bs,
                                              f32x4 acc[4][4]) {
  const int tid = threadIdx.x;
  const int lane = tid & 63;
  const int wid = tid >> 6;
  const int wm = wid >> 1, wn = wid & 1;
  const int c16 = lane & 15, rg = lane >> 4;

  for (int k0 = 0; k0 < 1024; k0 += 64) {
    __syncthreads();
#pragma unroll
    for (int i = 0; i < 4; ++i) {
      int e = (i * 256 + tid) * 8;       // element index within 128x64 tile
      int row = e >> 6;                  // 0..127
      int chunk = (e & 63) >> 3;         // 0..7 (16B chunk)
      int scol = ((chunk ^ (row & 7)) << 3);  // source-side swizzle (involution)
      gload_lds16(A + (size_t)(m0 + row) * 1024 + k0 + scol,
                  As + (size_t)(i * 256 + (wid << 6)) * 8);
      gload_lds16(Bmat + (size_t)(n0 + row) * 1024 + k0 + scol,
                  Bs + (size_t)(i * 256 + (wid << 6)) * 8);
    }
    __syncthreads();
#pragma unroll
    for (int kk = 0; kk < 2; ++kk) {
      half8 af[4], bfr[4];
#pragma unroll
      for (int mi = 0; mi < 4; ++mi) {
        int row = (wm << 6) + (mi << 4) + c16;
        int chunk = (kk << 2) + rg;
        af[mi] = *(const half8*)&As[(row << 6) + ((chunk ^ (row & 7)) << 3)];
      }
#pragma unroll
      for (int ni = 0; ni < 4; ++ni) {
        int row = (wn << 6) + (ni << 4) + c16;
        int chunk = (kk << 2) + rg;
        bfr[ni] = *(const half8*)&Bs[(row << 6) + ((chunk ^ (row & 7)) << 3)];
      }
#pragma unroll
      for (int mi = 0; mi < 4; ++mi)
#pragma unroll
        for (int ni = 0; ni < 4; ++ni)
          acc[mi][ni] = __builtin_amdgcn_mfma_f32_16x16x32_f16(af[mi], bfr[ni], acc[mi][ni], 0, 0, 0);
    }
  }
}

// ---------------- QKV GEMM + bias + RoPE + scatter ----------------
// Q,K -> [bh][t][d] (Q pre-scaled by 1/8); V -> transposed [bh][d][t]
__global__ __launch_bounds__(256, 2) void k_qkv(const _Float16* __restrict__ xh,
                                                const _Float16* __restrict__ WT,
                                                const float* __restrict__ bq,
                                                const float* __restrict__ bk,
                                                const float* __restrict__ bv,
                                                _Float16* __restrict__ Qh,
                                                _Float16* __restrict__ Kh,
                                                _Float16* __restrict__ VT) {
  __shared__ __align__(16) _Float16 As[128 * 64];
  __shared__ __align__(16) _Float16 Bs[128 * 64];
  f32x4 acc[4][4];
#pragma unroll
  for (int i = 0; i < 4; ++i)
#pragma unroll
    for (int j = 0; j < 4; ++j) acc[i][j] = (f32x4){0.f, 0.f, 0.f, 0.f};

  const int m0 = blockIdx.y * 128;
  const int ng = blockIdx.x * 128;   // 0..3071
  const int p = ng >> 10;            // 0=q,1=k,2=v
  const int n0 = ng & 1023;
  gemm_mainloop(xh, WT + ((size_t)p << 20), m0, n0, As, Bs, acc);

  const int tid = threadIdx.x, lane = tid & 63, wid = tid >> 6;
  const int wm = wid >> 1, wn = wid & 1, c16 = lane & 15, rg = lane >> 4;
  const float* bias = (p == 0) ? bq : (p == 1) ? bk : bv;
  const int nw = n0 + (wn << 6);
  const int head = nw >> 6;          // wave's 64-col strip is exactly one head
  float bi[4];
#pragma unroll
  for (int ni = 0; ni < 4; ++ni) bi[ni] = bias[nw + (ni << 4) + c16];

  if (p == 2) {  // V: store transposed [bh][d][t], vectorized half4 over t
#pragma unroll
    for (int mi = 0; mi < 4; ++mi) {
      int m = m0 + (wm << 6) + (mi << 4) + (rg << 2);
      int b = m >> 11, t0 = m & 2047;
#pragma unroll
      for (int ni = 0; ni < 4; ++ni) {
        half4 hv;
#pragma unroll
        for (int r = 0; r < 4; ++r) hv[r] = (_Float16)(acc[mi][ni][r] + bi[ni]);
        size_t base = ((size_t)(b * NH + head) * ND + (ni << 4) + c16) * NT + t0;
        *(half4*)&VT[base] = hv;
      }
    }
    return;
  }

  _Float16* Out = (p == 0) ? Qh : Kh;
  // inv_freq[c16] = 10000^(-c16/16) = 2^(-c16 * log2(10000)/16)  (accurate exp2)
  const float invf = exp2f((float)c16 * -0.8304820237218405f);
  const float qscale = (p == 0) ? 0.125f : 1.0f;   // fold 1/sqrt(D) into Q (exact pow2)

#pragma unroll
  for (int mi = 0; mi < 4; ++mi) {
#pragma unroll
    for (int r = 0; r < 4; ++r) {
      int m = m0 + (wm << 6) + (mi << 4) + (rg << 2) + r;
      int b = m >> 11, t = m & 2047;
      float v0 = acc[mi][0][r] + bi[0];
      float v1 = acc[mi][1][r] + bi[1];
      float v2 = acc[mi][2][r] + bi[2];
      float v3 = acc[mi][3][r] + bi[3];
      {  // RoPE on d<32: pair (d, d+16)
        float th = (float)t * invf;
        float sn, cs;
        sincosf(th, &sn, &cs);   // theta reaches 2047 rad: needs libm range reduction
        float nx = v0 * cs - v1 * sn;
        v1 = v1 * cs + v0 * sn;
        v0 = nx;
      }
      size_t base = ((size_t)(b * NH + head) * NT + t) * ND;
      Out[base + 0 + c16]  = (_Float16)(v0 * qscale);
      Out[base + 16 + c16] = (_Float16)(v1 * qscale);
      Out[base + 32 + c16] = (_Float16)(v2 * qscale);
      Out[base + 48 + c16] = (_Float16)(v3 * qscale);
    }
  }
}

// ---------------- flash attention, barrier-free ----------------
// block = (bh, 64 q-rows), 4 waves x 16 q-rows; KVBLK=64
// swapped QK^T (S^T = K*Q^T): per-lane P column for q=c16; softmax in-lane + 2 shfl
// V read direct from global V^T (L2-resident); P repacked via per-wave swizzled LDS
__global__ __launch_bounds__(256) void k_attn(const _Float16* __restrict__ Qh,
                                              const _Float16* __restrict__ Kh,
                                              const _Float16* __restrict__ VT,
                                              _Float16* __restrict__ Oh) {
  // XCD-bijective swizzle: 1024 blocks, 128/XCD -> 4 consecutive bh per XCD (K+V 2MB in L2)
  const int lin = blockIdx.y * 32 + blockIdx.x;
  const int sw = ((lin & 7) << 7) + (lin >> 3);
  const int bh = sw >> 5;
  const int q0 = (sw & 31) << 6;

  const int tid = threadIdx.x, lane = tid & 63, wid = tid >> 6;
  const int c16 = lane & 15, rg = lane >> 4;
  const size_t hb = (size_t)bh * NT * ND;   // base for Qh/Kh and (d-major) VT

  __shared__ unsigned int P_lds[4 * 16 * 32];  // per-wave [16 q][32 u32], xor-swizzled

  const int qg = q0 + (wid << 4) + c16;        // this lane's softmax-owned q row
  half8 qf0 = *(const half8*)&Qh[hb + (size_t)qg * ND + (rg << 3)];
  half8 qf1 = *(const half8*)&Qh[hb + (size_t)qg * ND + 32 + (rg << 3)];

  f32x4 oacc[4];
#pragma unroll
  for (int i = 0; i < 4; ++i) oacc[i] = (f32x4){0.f, 0.f, 0.f, 0.f};
  float m = -INFINITY, l = 0.f;

  const int pbase = ((wid << 4) + c16) << 5;
  const int psw = (c16 & 7) << 2;              // xor swizzle (units of u32, mult of 4)

  for (int kt = 0; kt < q0 + 64; kt += 64) {
    // ---- QK^T (swapped): s[ni] = S^T[kv=16ni+4rg+r][q=c16] ----
    f32x4 s[4];
#pragma unroll
    for (int ni = 0; ni < 4; ++ni) {
      const size_t krow = hb + (size_t)(kt + (ni << 4) + c16) * ND;
      half8 kf0 = *(const half8*)&Kh[krow + (rg << 3)];
      half8 kf1 = *(const half8*)&Kh[krow + 32 + (rg << 3)];
      f32x4 z = (f32x4){0.f, 0.f, 0.f, 0.f};
      z = __builtin_amdgcn_mfma_f32_16x16x32_f16(kf0, qf0, z, 0, 0, 0);
      s[ni] = __builtin_amdgcn_mfma_f32_16x16x32_f16(kf1, qf1, z, 0, 0, 0);
    }

    // ---- prefetch V^T fragments (independent of softmax; hides under VALU) ----
    half8 vf[2][4];
#pragma unroll
    for (int c = 0; c < 2; ++c)
#pragma unroll
      for (int ni = 0; ni < 4; ++ni)
        vf[c][ni] = *(const half8*)&VT[hb + (size_t)((ni << 4) + c16) * NT + kt + (c << 5) + (rg << 3)];

    // ---- mask + online softmax (state at q=c16 lanes) ----
    float pm = -INFINITY;
#pragma unroll
    for (int ni = 0; ni < 4; ++ni)
#pragma unroll
      for (int r = 0; r < 4; ++r) {
        int kv = kt + (ni << 4) + (rg << 2) + r;
        float v = (kv > qg) ? -INFINITY : s[ni][r];
        s[ni][r] = v;
        pm = fmaxf(pm, v);
      }
    pm = fmaxf(pm, __shfl_xor(pm, 16));
    pm = fmaxf(pm, __shfl_xor(pm, 32));

    if (!__all(pm <= m + 8.f)) {   // defer-max (THR=8): rescale only on real growth
      float mn = fmaxf(m, pm);
      float corr = __expf(m - mn);
      m = mn;
      l *= corr;
      float co[4];
#pragma unroll
      for (int r = 0; r < 4; ++r) co[r] = __shfl(corr, (rg << 2) + r);
#pragma unroll
      for (int ni = 0; ni < 4; ++ni)
#pragma unroll
        for (int r = 0; r < 4; ++r) oacc[ni][r] *= co[r];
    }

    float ps = 0.f;
#pragma unroll
    for (int ni = 0; ni < 4; ++ni)
#pragma unroll
      for (int r = 0; r < 4; ++r) {
        float pv = __expf(s[ni][r] - m);
        s[ni][r] = pv;
        ps += pv;
      }
    ps += __shfl_xor(ps, 16);
    ps += __shfl_xor(ps, 32);
    l += ps;

    // ---- pack P to fp16 and repack layout via per-wave LDS (no barrier) ----
#pragma unroll
    for (int ni = 0; ni < 4; ++ni) {
      uint2 w;
      w.x = __builtin_bit_cast(unsigned int, __builtin_amdgcn_cvt_pkrtz(s[ni][0], s[ni][1]));
      w.y = __builtin_bit_cast(unsigned int, __builtin_amdgcn_cvt_pkrtz(s[ni][2], s[ni][3]));
      *(uint2*)&P_lds[pbase + (((ni << 3) + (rg << 1)) ^ psw)] = w;
    }
    uint4 u0 = *(const uint4*)&P_lds[pbase + ((rg << 2) ^ psw)];
    uint4 u1 = *(const uint4*)&P_lds[pbase + ((16 + (rg << 2)) ^ psw)];
    half8 pa0 = __builtin_bit_cast(half8, u0);
    half8 pa1 = __builtin_bit_cast(half8, u1);

    // ---- PV: O[16 q][64 d] += P * V ----
#pragma unroll
    for (int ni = 0; ni < 4; ++ni)
      oacc[ni] = __builtin_amdgcn_mfma_f32_16x16x32_f16(pa0, vf[0][ni], oacc[ni], 0, 0, 0);
#pragma unroll
    for (int ni = 0; ni < 4; ++ni)
      oacc[ni] = __builtin_amdgcn_mfma_f32_16x16x32_f16(pa1, vf[1][ni], oacc[ni], 0, 0, 0);
  }

  // ---- epilogue: normalize, store O as [b*T+t][h*64+d] fp16 ----
  const int b = bh >> 4, h = bh & 15;
  float il = 1.f / l;
#pragma unroll
  for (int r = 0; r < 4; ++r) {
    float ilo = __shfl(il, (rg << 2) + r);
    int q = q0 + (wid << 4) + (rg << 2) + r;
    size_t base = ((size_t)b * NT + q) * NC + h * ND;
#pragma unroll
    for (int ni = 0; ni < 4; ++ni)
      Oh[base + (ni << 4) + c16] = (_Float16)(oacc[ni][r] * ilo);
  }
}

// ---------------- output projection GEMM (fp32 out + bias) ----------------
__global__ __launch_bounds__(256, 2) void k_out(const _Float16* __restrict__ Oh,
                                                const _Float16* __restrict__ WoT,
                                                const float* __restrict__ bo,
                                                float* __restrict__ out) {
  __shared__ __align__(16) _Float16 As[128 * 64];
  __shared__ __align__(16) _Float16 Bs[128 * 64];
  f32x4 acc[4][4];
#pragma unroll
  for (int i = 0; i < 4; ++i)
#pragma unroll
    for (int j = 0; j < 4; ++j) acc[i][j] = (f32x4){0.f, 0.f, 0.f, 0.f};

  const int m0 = blockIdx.y * 128;
  const int n0 = blockIdx.x * 128;
  gemm_mainloop(Oh, WoT, m0, n0, As, Bs, acc);

  const int tid = threadIdx.x, lane = tid & 63, wid = tid >> 6;
  const int wm = wid >> 1, wn = wid & 1, c16 = lane & 15, rg = lane >> 4;
  float bi[4];
#pragma unroll
  for (int ni = 0; ni < 4; ++ni) bi[ni] = bo[n0 + (wn << 6) + (ni << 4) + c16];
#pragma unroll
  for (int mi = 0; mi < 4; ++mi) {
#pragma unroll
    for (int r = 0; r < 4; ++r) {
      int m = m0 + (wm << 6) + (mi << 4) + (rg << 2) + r;
#pragma unroll
      for (int ni = 0; ni < 4; ++ni) {
        int n = n0 + (wn << 6) + (ni << 4) + c16;
        out[(size_t)m * NC + n] = acc[mi][ni][r] + bi[ni];
      }
    }
  }
}

extern "C" void kernel_launch(void* const* d_in, const int* in_sizes, int n_in,
                              void* d_out, int out_size, void* d_ws, size_t ws_size,
                              hipStream_t stream) {
  const float* x  = (const float*)d_in[0];
  const float* Wq = (const float*)d_in[1];
  const float* bq = (const float*)d_in[2];
  const float* Wk = (const float*)d_in[3];
  const float* bk = (const float*)d_in[4];
  const float* Wv = (const float*)d_in[5];
  const float* bv = (const float*)d_in[6];
  const float* Wo = (const float*)d_in[7];
  const float* bo = (const float*)d_in[8];
  float* out = (float*)d_out;

  char* ws = (char*)d_ws;
  _Float16* xh = (_Float16*)ws;                       // 8 MB  [4096][1024]
  _Float16* WT = (_Float16*)(ws + (8ull << 20));      // 8 MB  [4][1024][1024] n-major
  _Float16* Qh = (_Float16*)(ws + (16ull << 20));     // 8 MB  [32][2048][64]
  _Float16* Kh = (_Float16*)(ws + (24ull << 20));     // 8 MB  [32][2048][64]
  _Float16* Vt = (_Float16*)(ws + (32ull << 20));     // 8 MB  [32][64][2048] (transposed)
  _Float16* Oh = (_Float16*)(ws + (40ull << 20));     // 8 MB  [4096][1024]

  k_cvt_x<<<2048, 256, 0, stream>>>(x, xh);
  k_tw<<<dim3(32, 32, 4), dim3(32, 8), 0, stream>>>(Wq, Wk, Wv, Wo, WT);
  k_qkv<<<dim3(24, 32), 256, 0, stream>>>(xh, WT, bq, bk, bv, Qh, Kh, Vt);
  k_attn<<<dim3(32, 32), 256, 0, stream>>>(Qh, Kh, Vt, Oh);
  k_out<<<dim3(8, 32), 256, 0, stream>>>(Oh, WT + (3ull << 20), bo, out);
}

// Round 4
// 182.051 us; speedup vs baseline: 1.5823x; 1.5823x over previous
//
#include <hip/hip_runtime.h>
#include <cstdint>
#include <cstddef>
#include <math.h>

typedef _Float16 half8 __attribute__((ext_vector_type(8)));
typedef _Float16 half4 __attribute__((ext_vector_type(4)));
typedef float f32x4 __attribute__((ext_vector_type(4)));

#define NB  2
#define NT  2048
#define NC  1024
#define NH  16
#define ND  64

__device__ __forceinline__ void gload_lds16(const _Float16* g, _Float16* l) {
  __builtin_amdgcn_global_load_lds((const __attribute__((address_space(1))) void*)g,
                                   (__attribute__((address_space(3))) void*)l, 16, 0, 0);
}

// ---------------- convert x -> fp16 ----------------
__global__ void k_cvt_x(const float* __restrict__ x, _Float16* __restrict__ xh) {
  const int n4 = (4096 * 1024) / 4;
  int i = blockIdx.x * 256 + threadIdx.x;
  for (; i < n4; i += 2048 * 256) {
    float4 v = ((const float4*)x)[i];
    half4 h = { (_Float16)v.x, (_Float16)v.y, (_Float16)v.z, (_Float16)v.w };
    ((half4*)xh)[i] = h;
  }
}

// ------------- transpose+convert W (1024x1024) -> WT[n][k] fp16 -------------
__global__ void k_tw(const float* __restrict__ W0, const float* __restrict__ W1,
                     const float* __restrict__ W2, const float* __restrict__ W3,
                     _Float16* __restrict__ WT) {
  const float* W = (blockIdx.z == 0) ? W0 : (blockIdx.z == 1) ? W1 : (blockIdx.z == 2) ? W2 : W3;
  _Float16* out = WT + ((size_t)blockIdx.z << 20);
  __shared__ float t[32][33];
  const int x0 = blockIdx.x * 32;  // n
  const int y0 = blockIdx.y * 32;  // k
  const int tx = threadIdx.x, ty = threadIdx.y;  // (32,8)
#pragma unroll
  for (int r = 0; r < 4; ++r)
    t[ty + 8 * r][tx] = W[(size_t)(y0 + ty + 8 * r) * 1024 + x0 + tx];
  __syncthreads();
#pragma unroll
  for (int r = 0; r < 4; ++r)
    out[(size_t)(x0 + ty + 8 * r) * 1024 + y0 + tx] = (_Float16)t[tx][ty + 8 * r];
}

// ---------------- shared GEMM mainloop: C(128x128) = A(128xK) * B^T(128xK) ----------------
__device__ __forceinline__ void gemm_mainloop(const _Float16* __restrict__ A,
                                              const _Float16* __restrict__ Bmat,
                                              int m0, int n0,
                                              _Float16* As, _Float16* Bs,
                                              f32x4 acc[4][4]) {
  const int tid = threadIdx.x;
  const int lane = tid & 63;
  const int wid = tid >> 6;
  const int wm = wid >> 1, wn = wid & 1;
  const int c16 = lane & 15, rg = lane >> 4;

  for (int k0 = 0; k0 < 1024; k0 += 64) {
    __syncthreads();
#pragma unroll
    for (int i = 0; i < 4; ++i) {
      int e = (i * 256 + tid) * 8;       // element index within 128x64 tile
      int row = e >> 6;                  // 0..127
      int chunk = (e & 63) >> 3;         // 0..7 (16B chunk)
      int scol = ((chunk ^ (row & 7)) << 3);  // source-side swizzle (involution)
      gload_lds16(A + (size_t)(m0 + row) * 1024 + k0 + scol,
                  As + (size_t)(i * 256 + (wid << 6)) * 8);
      gload_lds16(Bmat + (size_t)(n0 + row) * 1024 + k0 + scol,
                  Bs + (size_t)(i * 256 + (wid << 6)) * 8);
    }
    __syncthreads();
#pragma unroll
    for (int kk = 0; kk < 2; ++kk) {
      half8 af[4], bfr[4];
#pragma unroll
      for (int mi = 0; mi < 4; ++mi) {
        int row = (wm << 6) + (mi << 4) + c16;
        int chunk = (kk << 2) + rg;
        af[mi] = *(const half8*)&As[(row << 6) + ((chunk ^ (row & 7)) << 3)];
      }
#pragma unroll
      for (int ni = 0; ni < 4; ++ni) {
        int row = (wn << 6) + (ni << 4) + c16;
        int chunk = (kk << 2) + rg;
        bfr[ni] = *(const half8*)&Bs[(row << 6) + ((chunk ^ (row & 7)) << 3)];
      }
#pragma unroll
      for (int mi = 0; mi < 4; ++mi)
#pragma unroll
        for (int ni = 0; ni < 4; ++ni)
          acc[mi][ni] = __builtin_amdgcn_mfma_f32_16x16x32_f16(af[mi], bfr[ni], acc[mi][ni], 0, 0, 0);
    }
  }
}

// ---------------- QKV GEMM + bias + RoPE + scatter ----------------
// Q,K -> [bh][t][d] (Q pre-scaled by 1/8); V -> transposed [bh][d][t]
__global__ __launch_bounds__(256, 2) void k_qkv(const _Float16* __restrict__ xh,
                                                const _Float16* __restrict__ WT,
                                                const float* __restrict__ bq,
                                                const float* __restrict__ bk,
                                                const float* __restrict__ bv,
                                                _Float16* __restrict__ Qh,
                                                _Float16* __restrict__ Kh,
                                                _Float16* __restrict__ VT) {
  __shared__ __align__(16) _Float16 As[128 * 64];
  __shared__ __align__(16) _Float16 Bs[128 * 64];
  f32x4 acc[4][4];
#pragma unroll
  for (int i = 0; i < 4; ++i)
#pragma unroll
    for (int j = 0; j < 4; ++j) acc[i][j] = (f32x4){0.f, 0.f, 0.f, 0.f};

  const int m0 = blockIdx.y * 128;
  const int ng = blockIdx.x * 128;   // 0..3071
  const int p = ng >> 10;            // 0=q,1=k,2=v
  const int n0 = ng & 1023;
  gemm_mainloop(xh, WT + ((size_t)p << 20), m0, n0, As, Bs, acc);

  const int tid = threadIdx.x, lane = tid & 63, wid = tid >> 6;
  const int wm = wid >> 1, wn = wid & 1, c16 = lane & 15, rg = lane >> 4;
  const float* bias = (p == 0) ? bq : (p == 1) ? bk : bv;
  const int nw = n0 + (wn << 6);
  const int head = nw >> 6;          // wave's 64-col strip is exactly one head
  float bi[4];
#pragma unroll
  for (int ni = 0; ni < 4; ++ni) bi[ni] = bias[nw + (ni << 4) + c16];

  if (p == 2) {  // V: store transposed [bh][d][t], vectorized half4 over t
#pragma unroll
    for (int mi = 0; mi < 4; ++mi) {
      int m = m0 + (wm << 6) + (mi << 4) + (rg << 2);
      int b = m >> 11, t0 = m & 2047;
#pragma unroll
      for (int ni = 0; ni < 4; ++ni) {
        half4 hv;
#pragma unroll
        for (int r = 0; r < 4; ++r) hv[r] = (_Float16)(acc[mi][ni][r] + bi[ni]);
        size_t base = ((size_t)(b * NH + head) * ND + (ni << 4) + c16) * NT + t0;
        *(half4*)&VT[base] = hv;
      }
    }
    return;
  }

  _Float16* Out = (p == 0) ? Qh : Kh;
  // inv_freq[c16] = 10000^(-c16/16) = 2^(-c16 * log2(10000)/16)  (accurate exp2)
  const float invf = exp2f((float)c16 * -0.8304820237218405f);
  const float qscale = (p == 0) ? 0.125f : 1.0f;   // fold 1/sqrt(D) into Q (exact pow2)

#pragma unroll
  for (int mi = 0; mi < 4; ++mi) {
#pragma unroll
    for (int r = 0; r < 4; ++r) {
      int m = m0 + (wm << 6) + (mi << 4) + (rg << 2) + r;
      int b = m >> 11, t = m & 2047;
      float v0 = acc[mi][0][r] + bi[0];
      float v1 = acc[mi][1][r] + bi[1];
      float v2 = acc[mi][2][r] + bi[2];
      float v3 = acc[mi][3][r] + bi[3];
      {  // RoPE on d<32: pair (d, d+16)
        float th = (float)t * invf;
        float sn, cs;
        sincosf(th, &sn, &cs);   // theta reaches 2047 rad: needs libm range reduction
        float nx = v0 * cs - v1 * sn;
        v1 = v1 * cs + v0 * sn;
        v0 = nx;
      }
      size_t base = ((size_t)(b * NH + head) * NT + t) * ND;
      Out[base + 0 + c16]  = (_Float16)(v0 * qscale);
      Out[base + 16 + c16] = (_Float16)(v1 * qscale);
      Out[base + 32 + c16] = (_Float16)(v2 * qscale);
      Out[base + 48 + c16] = (_Float16)(v3 * qscale);
    }
  }
}

// ---------------- flash attention, balanced pairs + K double-buffer ----------------
// 512 blocks; block handles q-tiles {pi, 31-pi} sequentially -> exactly 33 kv-iters each.
// swapped QK^T; per-lane softmax state at q=c16; V^T direct from L2; P via swizzled LDS.
__global__ __launch_bounds__(256, 2) void k_attn(const _Float16* __restrict__ Qh,
                                                 const _Float16* __restrict__ Kh,
                                                 const _Float16* __restrict__ VT,
                                                 _Float16* __restrict__ Oh) {
  // XCD swizzle: 512 blocks -> 64/XCD -> 4 consecutive bh per XCD (K+V 2MB in L2)
  const int lin = blockIdx.x;
  const int sw = ((lin & 7) << 6) + (lin >> 3);
  const int bh = sw >> 4;
  const int pi = sw & 15;

  const int tid = threadIdx.x, lane = tid & 63, wid = tid >> 6;
  const int c16 = lane & 15, rg = lane >> 4;
  const size_t hb = (size_t)bh * NT * ND;
  const _Float16* Qp = Qh + hb;
  const _Float16* Kp = Kh + hb;
  const _Float16* Vp = VT + hb;

  __shared__ unsigned int P_lds[4 * 16 * 32];  // per-wave [16 q][32 u32], xor-swizzled
  const int pbase = ((wid << 4) + c16) << 5;
  const int psw = (c16 & 7) << 2;

  const int b = bh >> 4, h = bh & 15;

#pragma unroll 1
  for (int half_sel = 0; half_sel < 2; ++half_sel) {
    const int q0 = (half_sel == 0 ? (31 - pi) : pi) << 6;   // long tile first
    const int end = q0 + 64;
    const int qg = q0 + (wid << 4) + c16;
    const int qwmin = q0 + (wid << 4);

    half8 qf0 = *(const half8*)&Qp[(size_t)qg * ND + (rg << 3)];
    half8 qf1 = *(const half8*)&Qp[(size_t)qg * ND + 32 + (rg << 3)];

    f32x4 oacc[4];
#pragma unroll
    for (int i = 0; i < 4; ++i) oacc[i] = (f32x4){0.f, 0.f, 0.f, 0.f};
    float m = -INFINITY, l = 0.f;

    half8 kA[8], kB[8], vf[8];

    // K-load into named buffer (static indexing)
#define LOADK(dst, ktv) do {                                                    \
      const _Float16* kp_ = Kp + (size_t)((ktv) + c16) * ND + (rg << 3);        \
      _Pragma("unroll")                                                         \
      for (int ni = 0; ni < 4; ++ni) {                                          \
        dst[2 * ni]     = *(const half8*)(kp_ + (size_t)(ni << 4) * ND);        \
        dst[2 * ni + 1] = *(const half8*)(kp_ + (size_t)(ni << 4) * ND + 32);   \
      } } while (0)

#define LOADV(ktv) do {                                                         \
      _Pragma("unroll")                                                         \
      for (int c = 0; c < 2; ++c)                                               \
        _Pragma("unroll")                                                       \
        for (int ni = 0; ni < 4; ++ni)                                          \
          vf[(c << 2) + ni] = *(const half8*)&Vp[(size_t)((ni << 4) + c16) * NT \
                                                 + (ktv) + (c << 5) + (rg << 3)]; \
      } while (0)

#define BODY(kb, ktc) do {                                                      \
      f32x4 s[4];                                                               \
      _Pragma("unroll")                                                         \
      for (int ni = 0; ni < 4; ++ni) {                                          \
        f32x4 z = (f32x4){0.f, 0.f, 0.f, 0.f};                                  \
        z = __builtin_amdgcn_mfma_f32_16x16x32_f16(kb[2 * ni], qf0, z, 0, 0, 0); \
        s[ni] = __builtin_amdgcn_mfma_f32_16x16x32_f16(kb[2 * ni + 1], qf1, z, 0, 0, 0); \
      }                                                                         \
      if ((ktc) + 63 > qwmin) {  /* causal mask needed (wave-uniform test) */   \
        _Pragma("unroll")                                                       \
        for (int ni = 0; ni < 4; ++ni)                                          \
          _Pragma("unroll")                                                     \
          for (int r = 0; r < 4; ++r) {                                         \
            int kv = (ktc) + (ni << 4) + (rg << 2) + r;                         \
            if (kv > qg) s[ni][r] = -INFINITY;                                  \
          }                                                                     \
      }                                                                         \
      float pm = -INFINITY;                                                     \
      _Pragma("unroll")                                                         \
      for (int ni = 0; ni < 4; ++ni)                                            \
        _Pragma("unroll")                                                       \
        for (int r = 0; r < 4; ++r) pm = fmaxf(pm, s[ni][r]);                   \
      pm = fmaxf(pm, __shfl_xor(pm, 16));                                       \
      pm = fmaxf(pm, __shfl_xor(pm, 32));                                       \
      if (!__all(pm <= m + 8.f)) {                                              \
        float mn = fmaxf(m, pm);                                                \
        float corr = __expf(m - mn);                                            \
        m = mn;                                                                 \
        l *= corr;                                                              \
        float co[4];                                                            \
        _Pragma("unroll")                                                       \
        for (int r = 0; r < 4; ++r) co[r] = __shfl(corr, (rg << 2) + r);        \
        _Pragma("unroll")                                                       \
        for (int ni = 0; ni < 4; ++ni)                                          \
          _Pragma("unroll")                                                     \
          for (int r = 0; r < 4; ++r) oacc[ni][r] *= co[r];                     \
      }                                                                         \
      float ps = 0.f;                                                           \
      _Pragma("unroll")                                                         \
      for (int ni = 0; ni < 4; ++ni)                                            \
        _Pragma("unroll")                                                       \
        for (int r = 0; r < 4; ++r) {                                           \
          float pv = __expf(s[ni][r] - m);                                      \
          s[ni][r] = pv;                                                        \
          ps += pv;                                                             \
        }                                                                       \
      ps += __shfl_xor(ps, 16);                                                 \
      ps += __shfl_xor(ps, 32);                                                 \
      l += ps;                                                                  \
      _Pragma("unroll")                                                         \
      for (int ni = 0; ni < 4; ++ni) {                                          \
        uint2 w;                                                                \
        w.x = __builtin_bit_cast(unsigned int, __builtin_amdgcn_cvt_pkrtz(s[ni][0], s[ni][1])); \
        w.y = __builtin_bit_cast(unsigned int, __builtin_amdgcn_cvt_pkrtz(s[ni][2], s[ni][3])); \
        *(uint2*)&P_lds[pbase + (((ni << 3) + (rg << 1)) ^ psw)] = w;           \
      }                                                                         \
      uint4 u0 = *(const uint4*)&P_lds[pbase + ((rg << 2) ^ psw)];              \
      uint4 u1 = *(const uint4*)&P_lds[pbase + ((16 + (rg << 2)) ^ psw)];       \
      half8 pa0 = __builtin_bit_cast(half8, u0);                                \
      half8 pa1 = __builtin_bit_cast(half8, u1);                                \
      _Pragma("unroll")                                                         \
      for (int ni = 0; ni < 4; ++ni)                                            \
        oacc[ni] = __builtin_amdgcn_mfma_f32_16x16x32_f16(pa0, vf[ni], oacc[ni], 0, 0, 0); \
      _Pragma("unroll")                                                         \
      for (int ni = 0; ni < 4; ++ni)                                            \
        oacc[ni] = __builtin_amdgcn_mfma_f32_16x16x32_f16(pa1, vf[4 + ni], oacc[ni], 0, 0, 0); \
    } while (0)

    // pipelined kv loop: K double-buffered (next tile's K in flight during softmax+PV)
    int kt = 0;
    LOADK(kA, 0);
    for (;;) {
      LOADV(kt);
      if (kt + 64 < end) LOADK(kB, kt + 64);
      BODY(kA, kt);
      kt += 64;
      if (kt >= end) break;
      LOADV(kt);
      if (kt + 64 < end) LOADK(kA, kt + 64);
      BODY(kB, kt);
      kt += 64;
      if (kt >= end) break;
    }
#undef LOADK
#undef LOADV
#undef BODY

    // epilogue: normalize, store O as [b*T+t][h*64+d] fp16
    float il = 1.f / l;
#pragma unroll
    for (int r = 0; r < 4; ++r) {
      float ilo = __shfl(il, (rg << 2) + r);
      int q = q0 + (wid << 4) + (rg << 2) + r;
      size_t base = ((size_t)b * NT + q) * NC + h * ND;
#pragma unroll
      for (int ni = 0; ni < 4; ++ni)
        Oh[base + (ni << 4) + c16] = (_Float16)(oacc[ni][r] * ilo);
    }
  }
}

// ---------------- output projection GEMM (fp32 out + bias) ----------------
__global__ __launch_bounds__(256, 2) void k_out(const _Float16* __restrict__ Oh,
                                                const _Float16* __restrict__ WoT,
                                                const float* __restrict__ bo,
                                                float* __restrict__ out) {
  __shared__ __align__(16) _Float16 As[128 * 64];
  __shared__ __align__(16) _Float16 Bs[128 * 64];
  f32x4 acc[4][4];
#pragma unroll
  for (int i = 0; i < 4; ++i)
#pragma unroll
    for (int j = 0; j < 4; ++j) acc[i][j] = (f32x4){0.f, 0.f, 0.f, 0.f};

  const int m0 = blockIdx.y * 128;
  const int n0 = blockIdx.x * 128;
  gemm_mainloop(Oh, WoT, m0, n0, As, Bs, acc);

  const int tid = threadIdx.x, lane = tid & 63, wid = tid >> 6;
  const int wm = wid >> 1, wn = wid & 1, c16 = lane & 15, rg = lane >> 4;
  float bi[4];
#pragma unroll
  for (int ni = 0; ni < 4; ++ni) bi[ni] = bo[n0 + (wn << 6) + (ni << 4) + c16];
#pragma unroll
  for (int mi = 0; mi < 4; ++mi) {
#pragma unroll
    for (int r = 0; r < 4; ++r) {
      int m = m0 + (wm << 6) + (mi << 4) + (rg << 2) + r;
#pragma unroll
      for (int ni = 0; ni < 4; ++ni) {
        int n = n0 + (wn << 6) + (ni << 4) + c16;
        out[(size_t)m * NC + n] = acc[mi][ni][r] + bi[ni];
      }
    }
  }
}

extern "C" void kernel_launch(void* const* d_in, const int* in_sizes, int n_in,
                              void* d_out, int out_size, void* d_ws, size_t ws_size,
                              hipStream_t stream) {
  const float* x  = (const float*)d_in[0];
  const float* Wq = (const float*)d_in[1];
  const float* bq = (const float*)d_in[2];
  const float* Wk = (const float*)d_in[3];
  const float* bk = (const float*)d_in[4];
  const float* Wv = (const float*)d_in[5];
  const float* bv = (const float*)d_in[6];
  const float* Wo = (const float*)d_in[7];
  const float* bo = (const float*)d_in[8];
  float* out = (float*)d_out;

  char* ws = (char*)d_ws;
  _Float16* xh = (_Float16*)ws;                       // 8 MB  [4096][1024]
  _Float16* WT = (_Float16*)(ws + (8ull << 20));      // 8 MB  [4][1024][1024] n-major
  _Float16* Qh = (_Float16*)(ws + (16ull << 20));     // 8 MB  [32][2048][64]
  _Float16* Kh = (_Float16*)(ws + (24ull << 20));     // 8 MB  [32][2048][64]
  _Float16* Vt = (_Float16*)(ws + (32ull << 20));     // 8 MB  [32][64][2048] (transposed)
  _Float16* Oh = (_Float16*)(ws + (40ull << 20));     // 8 MB  [4096][1024]

  k_cvt_x<<<2048, 256, 0, stream>>>(x, xh);
  k_tw<<<dim3(32, 32, 4), dim3(32, 8), 0, stream>>>(Wq, Wk, Wv, Wo, WT);
  k_qkv<<<dim3(24, 32), 256, 0, stream>>>(xh, WT, bq, bk, bv, Qh, Kh, Vt);
  k_attn<<<512, 256, 0, stream>>>(Qh, Kh, Vt, Oh);
  k_out<<<dim3(8, 32), 256, 0, stream>>>(Oh, WT + (3ull << 20), bo, out);
}